// Round 16
// baseline (156.782 us; speedup 1.0000x reference)
//
#include <hip/hip_runtime.h>

#define B_ 16
#define N_ 768
#define E_ 1024
#define H_ 16
#define D_ 64

typedef __bf16 bf16x8 __attribute__((ext_vector_type(8)));
typedef float f32x4 __attribute__((ext_vector_type(4)));
typedef unsigned short ushort8 __attribute__((ext_vector_type(8)));
typedef unsigned short ushort4v __attribute__((ext_vector_type(4)));
typedef unsigned int uint2v __attribute__((ext_vector_type(2)));
typedef unsigned int uint4v __attribute__((ext_vector_type(4)));

__device__ __forceinline__ unsigned short f2bf(float x) {
  unsigned u = __builtin_bit_cast(unsigned, x);
  u += 0x7FFFu + ((u >> 16) & 1u);
  return (unsigned short)(u >> 16);
}

__device__ __forceinline__ unsigned cvtpk(float lo, float hi) {
  unsigned r;
  asm("v_cvt_pk_bf16_f32 %0, %1, %2" : "=v"(r) : "v"(lo), "v"(hi));
  return r;
}

__device__ __forceinline__ float fexp2(float x) {
  float r;
  asm("v_exp_f32 %0, %1" : "=v"(r) : "v"(x));
  return r;
}

__device__ __forceinline__ f32x4 mfma16(ushort8 a, ushort8 b, f32x4 c) {
  return __builtin_amdgcn_mfma_f32_16x16x32_bf16(
      __builtin_bit_cast(bf16x8, a), __builtin_bit_cast(bf16x8, b), c, 0, 0, 0);
}

// pack 8 consecutive f32 (two float4) into a bf16x8 fragment (RNE)
__device__ __forceinline__ ushort8 pack8(float4 u, float4 v) {
  uint4v pk;
  pk[0] = cvtpk(u.x, u.y);
  pk[1] = cvtpk(u.z, u.w);
  pk[2] = cvtpk(v.x, v.y);
  pk[3] = cvtpk(v.z, v.w);
  return __builtin_bit_cast(ushort8, pk);
}

// ---------------- per-head projections: barrier-free streaming + reg double-buffer ----------------
// R13's verified barrier-free/LDS-free math; t-loop FULLY unrolled with tile
// t+1's 8 global loads issued BEFORE tile t's registers are consumed (the T14
// prefetch R13 omitted). Static buffer indices (no scratch, rule #20).
__global__ __launch_bounds__(256, 2) void proj_kernel(
    const float* __restrict__ q, const float* __restrict__ k, const float* __restrict__ v,
    const float* __restrict__ Wq, const float* __restrict__ Wk, const float* __restrict__ Wv,
    const float* __restrict__ Wf, unsigned short* __restrict__ Qh,
    unsigned short* __restrict__ Kh, unsigned short* __restrict__ Vt,
    unsigned short* __restrict__ Wfb) {
  const int m = blockIdx.x / 768;          // 0=q, 1=k, 2=v
  const int rest = blockIdx.x - m * 768;
  const int ng = rest % 3;                 // group of 256 rows
  const int bh = rest / 3;
  const int b = bh >> 4, h = bh & 15;
  const int tid = threadIdx.x;
  const int w = tid >> 6, l = tid & 63;
  const int l16 = l & 15, lg = l >> 4;

  const float* xp = (m == 0) ? q : (m == 1) ? k : v;
  const float* wp = ((m == 0) ? Wq : (m == 1) ? Wk : Wv) + (size_t)h * 4096;
  unsigned short* op = (m == 0) ? Qh : Kh;

  if (blockIdx.x < 1024) {  // fused Wf -> bf16 (independent elementwise)
    float4 wfv = *(const float4*)&Wf[((size_t)blockIdx.x * 256 + tid) * 4];
    ushort4v s;
    s[0] = f2bf(wfv.x); s[1] = f2bf(wfv.y); s[2] = f2bf(wfv.z); s[3] = f2bf(wfv.w);
    *(ushort4v*)&Wfb[((size_t)blockIdx.x * 256 + tid) * 4] = s;
  }

  // W fragments direct from global (L2-hot: 16KB reused by 48 blocks).
  ushort8 bw[4][2];
#pragma unroll
  for (int eg = 0; eg < 4; ++eg)
#pragma unroll
    for (int kc = 0; kc < 2; ++kc) {
      const float* wb = wp + (eg * 16 + l16) * 64 + kc * 32 + lg * 8;
      bw[eg][kc] = pack8(*(const float4*)wb, *(const float4*)(wb + 4));
    }

  const int bn0base = ng * 256 + w * 16;  // + t*64
  const size_t colbase = (size_t)h * 64;

  float4 xa0[2][2], xa1[2][2];  // two named buffers (static indexing)

  // prologue: tile 0 loads in flight
  {
    const size_t rowbase = ((size_t)(b * N_ + bn0base + l16)) * E_ + colbase;
#pragma unroll
    for (int kc = 0; kc < 2; ++kc) {
      const float* xb = xp + rowbase + kc * 32 + lg * 8;
      xa0[kc][0] = *(const float4*)xb;
      xa0[kc][1] = *(const float4*)(xb + 4);
    }
  }

#pragma unroll
  for (int t = 0; t < 4; ++t) {
    // issue tile t+1 loads into the OTHER buffer before consuming tile t
    if (t < 3) {
      const size_t rowbase = ((size_t)(b * N_ + bn0base + (t + 1) * 64 + l16)) * E_ + colbase;
#pragma unroll
      for (int kc = 0; kc < 2; ++kc) {
        const float* xb = xp + rowbase + kc * 32 + lg * 8;
        if ((t & 1) == 0) {
          xa1[kc][0] = *(const float4*)xb;
          xa1[kc][1] = *(const float4*)(xb + 4);
        } else {
          xa0[kc][0] = *(const float4*)xb;
          xa0[kc][1] = *(const float4*)(xb + 4);
        }
      }
    }

    f32x4 acc[4] = {};
#pragma unroll
    for (int kc = 0; kc < 2; ++kc) {
      ushort8 a = ((t & 1) == 0) ? pack8(xa0[kc][0], xa0[kc][1])
                                 : pack8(xa1[kc][0], xa1[kc][1]);
#pragma unroll
      for (int eg = 0; eg < 4; ++eg) acc[eg] = mfma16(a, bw[eg][kc], acc[eg]);
    }

    const int bn0 = bn0base + t * 64;
    if (m < 2) {
      // C layout: (row = lg*4+r [n-local], col = eg*16+l16 [d]) -> (B,H,N,D)
#pragma unroll
      for (int eg = 0; eg < 4; ++eg)
#pragma unroll
        for (int r = 0; r < 4; ++r)
          op[((size_t)bh * N_ + bn0 + lg * 4 + r) * 64 + eg * 16 + l16] = f2bf(acc[eg][r]);
    } else {
      // Vt (B,H,D,N): lane's 4 r-values are consecutive n at fixed d -> 8B store
#pragma unroll
      for (int eg = 0; eg < 4; ++eg) {
        uint2v pk;
        pk[0] = cvtpk(acc[eg][0], acc[eg][1]);
        pk[1] = cvtpk(acc[eg][2], acc[eg][3]);
        *(uint2v*)&Vt[((size_t)bh * 64 + eg * 16 + l16) * N_ + bn0 + lg * 4] = pk;
      }
    }
  }
}

// ---------------- flash attention per (b,h,qtile=128) — R14 text verbatim ----------------
__global__ __launch_bounds__(256, 4) void attn_kernel(
    const unsigned short* __restrict__ Qh, const unsigned short* __restrict__ Kh,
    const unsigned short* __restrict__ Vt, const float* __restrict__ mask,
    unsigned short* __restrict__ attnO) {
  const int bid = blockIdx.x;
  const int logical = (bid & 7) * 192 + (bid >> 3);  // XCD-chunked swizzle (1536%8==0)
  const int qt = logical % 6;
  const int bh = logical / 6;
  const int b = bh >> 4, h = bh & 15;
  const int tid = threadIdx.x;
  const int w = tid >> 6, l = tid & 63;
  const int l16 = l & 15, lg = l >> 4;

  __shared__ __align__(16) unsigned short Ks[64][72];
  __shared__ __align__(16) unsigned short Vs[64][72];
  __shared__ float addk[N_];

  const size_t baseK = (size_t)bh * N_ * 64;  // Kh (B,H,N,D)
  const size_t baseV = (size_t)bh * 64 * N_;  // Vt (B,H,D,N)
  const int qrow0 = qt * 128 + w * 32;
  const float C2 = 0.04508422f;  // log2(e)/32

  for (int i = tid; i < N_; i += 256)
    addk[i] = (mask[h * N_ + i] < -1e30f) ? -1.0e20f : 0.0f;

  ushort8 bQ[2][2];
#pragma unroll
  for (int qs = 0; qs < 2; ++qs)
#pragma unroll
    for (int kc = 0; kc < 2; ++kc)
      bQ[qs][kc] = *(const ushort8*)&Qh[((size_t)bh * N_ + qrow0 + qs * 16 + l16) * 64 +
                                        kc * 32 + lg * 8];
  float bqf[2];
#pragma unroll
  for (int qs = 0; qs < 2; ++qs)
    bqf[qs] = (mask[h * N_ + qrow0 + qs * 16 + l16] < -1e30f) ? 1.f : 0.f;

  // all-ones B fragment (bf16 1.0 = 0x3F80): ones-MFMA gives row-sums of P
  ushort8 ones8;
#pragma unroll
  for (int i = 0; i < 8; ++i) ones8[i] = 0x3F80u;

  const int srow = tid >> 3;
  const int sc8 = (tid & 7) * 8;

  uint4v kreg[2], vreg[2];
#pragma unroll
  for (int i = 0; i < 2; ++i) {
    int row = i * 32 + srow;
    kreg[i] = *(const uint4v*)&Kh[baseK + (size_t)row * 64 + sc8];
    vreg[i] = *(const uint4v*)&Vt[baseV + (size_t)row * N_ + sc8];
  }
  __syncthreads();  // addk ready
#pragma unroll
  for (int i = 0; i < 2; ++i) {
    int row = i * 32 + srow;
    *(ushort8*)&Ks[row][sc8] = __builtin_bit_cast(ushort8, kreg[i]);
    *(ushort8*)&Vs[row][sc8] = __builtin_bit_cast(ushort8, vreg[i]);
  }
  __syncthreads();

  f32x4 oacc[2][4] = {};
  f32x4 dacc[2] = {};

  for (int kt = 0; kt < 12; ++kt) {
    if (kt < 11) {  // T14: issue next-tile loads early, write after barrier
#pragma unroll
      for (int i = 0; i < 2; ++i) {
        int row = i * 32 + srow;
        kreg[i] = *(const uint4v*)&Kh[baseK + (size_t)((kt + 1) * 64 + row) * 64 + sc8];
        vreg[i] = *(const uint4v*)&Vt[baseV + (size_t)row * N_ + (kt + 1) * 64 + sc8];
      }
    }

    f32x4 st[4][2] = {};
#pragma unroll
    for (int kc = 0; kc < 2; ++kc) {
#pragma unroll
      for (int cg = 0; cg < 4; ++cg) {
        ushort8 aK = *(const ushort8*)&Ks[cg * 16 + l16][kc * 32 + lg * 8];
        st[cg][0] = mfma16(aK, bQ[0][kc], st[cg][0]);
        st[cg][1] = mfma16(aK, bQ[1][kc], st[cg][1]);
      }
    }

#pragma unroll
    for (int cg = 0; cg < 4; ++cg) {
      f32x4 ak4 = *(const f32x4*)&addk[kt * 64 + cg * 16 + lg * 4];
#pragma unroll
      for (int qs = 0; qs < 2; ++qs) {
#pragma unroll
        for (int r = 0; r < 4; ++r) {
          float t = __builtin_fmaf(st[cg][qs][r], C2, ak4[r]);
          t = (bqf[qs] > 0.f) ? 0.0f : t;
          st[cg][qs][r] = fexp2(t);
        }
      }
    }

#pragma unroll
    for (int kcP = 0; kcP < 2; ++kcP) {
      ushort8 pa[2];
#pragma unroll
      for (int qs = 0; qs < 2; ++qs) {
        unsigned a0 = cvtpk(st[2 * kcP][qs][0], st[2 * kcP][qs][1]);
        unsigned b0 = cvtpk(st[2 * kcP][qs][2], st[2 * kcP][qs][3]);
        unsigned a1 = cvtpk(st[2 * kcP + 1][qs][0], st[2 * kcP + 1][qs][1]);
        unsigned b1 = cvtpk(st[2 * kcP + 1][qs][2], st[2 * kcP + 1][qs][3]);
        asm("v_permlane32_swap_b32 %0, %1" : "+v"(a0), "+v"(a1));
        asm("v_permlane16_swap_b32 %0, %1" : "+v"(a0), "+v"(a1));
        asm("v_permlane32_swap_b32 %0, %1" : "+v"(b0), "+v"(b1));
        asm("v_permlane16_swap_b32 %0, %1" : "+v"(b0), "+v"(b1));
        uint4v pk;
        pk[0] = a0; pk[1] = b0; pk[2] = a1; pk[3] = b1;
        pa[qs] = __builtin_bit_cast(ushort8, pk);
      }
#pragma unroll
      for (int dg = 0; dg < 4; ++dg) {
        ushort8 bv = *(const ushort8*)&Vs[dg * 16 + l16][kcP * 32 + lg * 8];
        oacc[0][dg] = mfma16(pa[0], bv, oacc[0][dg]);
        oacc[1][dg] = mfma16(pa[1], bv, oacc[1][dg]);
      }
      dacc[0] = mfma16(pa[0], ones8, dacc[0]);  // row-sum of P -> denom
      dacc[1] = mfma16(pa[1], ones8, dacc[1]);
    }

    __syncthreads();  // all waves done reading K/V tile
    if (kt < 11) {
#pragma unroll
      for (int i = 0; i < 2; ++i) {
        int row = i * 32 + srow;
        *(ushort8*)&Ks[row][sc8] = __builtin_bit_cast(ushort8, kreg[i]);
        *(ushort8*)&Vs[row][sc8] = __builtin_bit_cast(ushort8, vreg[i]);
      }
    }
    __syncthreads();  // next tile visible
  }

  // epilogue: dacc[qs][r] is already the denominator for q = qrow0+qs*16+lg*4+r
#pragma unroll
  for (int qs = 0; qs < 2; ++qs) {
#pragma unroll
    for (int r = 0; r < 4; ++r) {
      float inv = 1.f / dacc[qs][r];
      int qg = qrow0 + qs * 16 + lg * 4 + r;
      size_t orow = ((size_t)b * N_ + qg) * E_ + h * 64;
#pragma unroll
      for (int dg = 0; dg < 4; ++dg)
        attnO[orow + dg * 16 + l16] = f2bf(oacc[qs][dg][r] * inv);
    }
  }
}

// ---------------- final GEMM: out = attn @ Wf^T — R14 text verbatim ----------------
__global__ __launch_bounds__(256) void gemm_kernel(const unsigned short* __restrict__ A,
                                                   const unsigned short* __restrict__ Bm,
                                                   float* __restrict__ out) {
  const int be = blockIdx.x & 7;   // Wf panel per XCD (L2 locality)
  const int bm = blockIdx.x >> 3;
  const int tid = threadIdx.x;
  const int w = tid >> 6, l = tid & 63;
  const int l16 = l & 15, lg = l >> 4;
  const int wm = w >> 1, wn = w & 1;

  __shared__ __align__(16) unsigned short As[128][72];
  __shared__ __align__(16) unsigned short Bs[128][72];

  f32x4 acc[4][4] = {};
  const int m0 = bm * 128, e0 = be * 128;
  const int srow = tid >> 3, sc8 = (tid & 7) * 8;
  const unsigned short* Ab = A + (size_t)(m0 + srow) * E_ + sc8;
  const unsigned short* Bb = Bm + (size_t)(e0 + srow) * E_ + sc8;

  uint4v ar[4], br[4];
#pragma unroll
  for (int i = 0; i < 4; ++i) {
    ar[i] = *(const uint4v*)(Ab + (size_t)i * 32 * E_);
    br[i] = *(const uint4v*)(Bb + (size_t)i * 32 * E_);
  }

  for (int kk = 0; kk < 16; ++kk) {
    __syncthreads();  // prev-tile reads done
#pragma unroll
    for (int i = 0; i < 4; ++i) {
      *(ushort8*)&As[i * 32 + srow][sc8] = __builtin_bit_cast(ushort8, ar[i]);
      *(ushort8*)&Bs[i * 32 + srow][sc8] = __builtin_bit_cast(ushort8, br[i]);
    }
    __syncthreads();  // tile ready
    if (kk < 15) {    // issue next-tile loads; overlap with MFMAs below
#pragma unroll
      for (int i = 0; i < 4; ++i) {
        ar[i] = *(const uint4v*)(Ab + (size_t)i * 32 * E_ + (kk + 1) * 64);
        br[i] = *(const uint4v*)(Bb + (size_t)i * 32 * E_ + (kk + 1) * 64);
      }
    }
#pragma unroll
    for (int kc = 0; kc < 2; ++kc) {
      ushort8 a[4], bf[4];
#pragma unroll
      for (int i = 0; i < 4; ++i)
        a[i] = *(const ushort8*)&As[wm * 64 + i * 16 + l16][kc * 32 + lg * 8];
#pragma unroll
      for (int j = 0; j < 4; ++j)
        bf[j] = *(const ushort8*)&Bs[wn * 64 + j * 16 + l16][kc * 32 + lg * 8];
#pragma unroll
      for (int i = 0; i < 4; ++i)
#pragma unroll
        for (int j = 0; j < 4; ++j) acc[i][j] = mfma16(a[i], bf[j], acc[i][j]);
    }
  }

#pragma unroll
  for (int i = 0; i < 4; ++i)
#pragma unroll
    for (int j = 0; j < 4; ++j)
#pragma unroll
      for (int r = 0; r < 4; ++r)
        out[(size_t)(m0 + wm * 64 + i * 16 + lg * 4 + r) * E_ + e0 + wn * 64 + j * 16 + l16] =
            acc[i][j][r];
}

extern "C" void kernel_launch(void* const* d_in, const int* in_sizes, int n_in,
                              void* d_out, int out_size, void* d_ws, size_t ws_size,
                              hipStream_t stream) {
  const float* q = (const float*)d_in[0];
  const float* k = (const float*)d_in[1];
  const float* v = (const float*)d_in[2];
  const float* mask = (const float*)d_in[3];
  const float* Wq = (const float*)d_in[4];
  const float* Wk = (const float*)d_in[5];
  const float* Wv = (const float*)d_in[6];
  const float* Wf = (const float*)d_in[7];
  float* out = (float*)d_out;

  const size_t PH = (size_t)B_ * H_ * N_ * D_;
  unsigned short* Qh = (unsigned short*)d_ws;
  unsigned short* Kh = Qh + PH;
  unsigned short* Vt = Kh + PH;
  unsigned short* attn = Vt + PH;
  unsigned short* Wfb = attn + PH;

  proj_kernel<<<3 * B_ * H_ * (N_ / 256), 256, 0, stream>>>(q, k, v, Wq, Wk, Wv, Wf, Qh, Kh,
                                                            Vt, Wfb);
  attn_kernel<<<B_ * H_ * (N_ / 128), 256, 0, stream>>>(Qh, Kh, Vt, mask, attn);
  gemm_kernel<<<(B_ * N_ / 128) * (E_ / 128), 256, 0, stream>>>(attn, Wfb, out);
}

// Round 17
// 133.196 us; speedup vs baseline: 1.1771x; 1.1771x over previous
//
#include <hip/hip_runtime.h>

#define B_ 16
#define N_ 768
#define E_ 1024
#define H_ 16
#define D_ 64

typedef __bf16 bf16x8 __attribute__((ext_vector_type(8)));
typedef float f32x4 __attribute__((ext_vector_type(4)));
typedef unsigned short ushort8 __attribute__((ext_vector_type(8)));
typedef unsigned short ushort4v __attribute__((ext_vector_type(4)));
typedef unsigned int uint2v __attribute__((ext_vector_type(2)));
typedef unsigned int uint4v __attribute__((ext_vector_type(4)));

__device__ __forceinline__ unsigned short f2bf(float x) {
  unsigned u = __builtin_bit_cast(unsigned, x);
  u += 0x7FFFu + ((u >> 16) & 1u);
  return (unsigned short)(u >> 16);
}

__device__ __forceinline__ unsigned cvtpk(float lo, float hi) {
  unsigned r;
  asm("v_cvt_pk_bf16_f32 %0, %1, %2" : "=v"(r) : "v"(lo), "v"(hi));
  return r;
}

__device__ __forceinline__ float fexp2(float x) {
  float r;
  asm("v_exp_f32 %0, %1" : "=v"(r) : "v"(x));
  return r;
}

__device__ __forceinline__ f32x4 mfma16(ushort8 a, ushort8 b, f32x4 c) {
  return __builtin_amdgcn_mfma_f32_16x16x32_bf16(
      __builtin_bit_cast(bf16x8, a), __builtin_bit_cast(bf16x8, b), c, 0, 0, 0);
}

// ---------------- per-head projections: R12 staged structure + 2-deep prefetch ----------------
// Identical barriers/indices/math to the R12-verified kernel; only change is
// register prefetch depth 1 -> 2 (tiles 0,1 loaded in prologue; iteration t
// prefetches tile t+2 into the parity buffer it just consumed).
__global__ __launch_bounds__(256, 2) void proj_kernel(
    const float* __restrict__ q, const float* __restrict__ k, const float* __restrict__ v,
    const float* __restrict__ Wq, const float* __restrict__ Wk, const float* __restrict__ Wv,
    const float* __restrict__ Wf, unsigned short* __restrict__ Qh,
    unsigned short* __restrict__ Kh, unsigned short* __restrict__ Vt,
    unsigned short* __restrict__ Wfb) {
  const int m = blockIdx.x / 768;          // 0=q, 1=k, 2=v
  const int rest = blockIdx.x - m * 768;
  const int ng = rest % 3;                 // group of 4 n-tiles
  const int bh = rest / 3;
  const int b = bh >> 4, h = bh & 15;
  const int nt0 = ng * 4;
  const int tid = threadIdx.x;
  const int w = tid >> 6, l = tid & 63;
  const int l16 = l & 15, lg = l >> 4;

  __shared__ __align__(16) unsigned short Xs[64][72];
  __shared__ __align__(16) unsigned short Ws[64][72];
  __shared__ __align__(16) unsigned short Os[64][72];

  const float* xp = (m == 0) ? q : (m == 1) ? k : v;
  const float* wp = ((m == 0) ? Wq : (m == 1) ? Wk : Wv) + (size_t)h * 4096;
  unsigned short* op = (m == 0) ? Qh : Kh;

  const int row = tid >> 4;            // 0..15 (+16i)
  const int c4 = (tid & 15) * 4;

  // prologue: weight + tiles 0 AND 1 loads all in flight (2-deep)
  float4 wt[4], xa[4], xb[4];
#pragma unroll
  for (int i = 0; i < 4; ++i)
    wt[i] = *(const float4*)&wp[(i * 16 + row) * 64 + c4];
#pragma unroll
  for (int i = 0; i < 4; ++i)
    xa[i] = *(const float4*)&xp[((size_t)(b * N_ + nt0 * 64 + i * 16 + row)) * E_ + h * 64 + c4];
#pragma unroll
  for (int i = 0; i < 4; ++i)
    xb[i] = *(const float4*)&xp[((size_t)(b * N_ + (nt0 + 1) * 64 + i * 16 + row)) * E_ +
                                h * 64 + c4];

  float4 wfv;
  if (blockIdx.x < 1024)  // fused Wf -> bf16 (independent elementwise)
    wfv = *(const float4*)&Wf[((size_t)blockIdx.x * 256 + tid) * 4];

#pragma unroll
  for (int i = 0; i < 4; ++i) {
    ushort4v s;
    s[0] = f2bf(wt[i].x); s[1] = f2bf(wt[i].y); s[2] = f2bf(wt[i].z); s[3] = f2bf(wt[i].w);
    *(ushort4v*)&Ws[i * 16 + row][c4] = s;
  }
  if (blockIdx.x < 1024) {
    ushort4v s;
    s[0] = f2bf(wfv.x); s[1] = f2bf(wfv.y); s[2] = f2bf(wfv.z); s[3] = f2bf(wfv.w);
    *(ushort4v*)&Wfb[((size_t)blockIdx.x * 256 + tid) * 4] = s;
  }

#pragma unroll
  for (int t = 0; t < 4; ++t) {
    // stage X tile t from its parity buffer (consumed here, freed for t+2)
#pragma unroll
    for (int i = 0; i < 4; ++i) {
      float4 xv = ((t & 1) == 0) ? xa[i] : xb[i];
      ushort4v s;
      s[0] = f2bf(xv.x); s[1] = f2bf(xv.y); s[2] = f2bf(xv.z); s[3] = f2bf(xv.w);
      *(ushort4v*)&Xs[i * 16 + row][c4] = s;
    }
    __syncthreads();  // tile ready; prior Os store-reads retired

    if (t < 2) {  // 2-deep prefetch: tile t+2 into the buffer just consumed
#pragma unroll
      for (int i = 0; i < 4; ++i) {
        float4 xv = *(const float4*)&xp[((size_t)(b * N_ + (nt0 + t + 2) * 64 + i * 16 + row)) *
                                            E_ + h * 64 + c4];
        if ((t & 1) == 0) xa[i] = xv; else xb[i] = xv;
      }
    }

    f32x4 acc[4] = {};
#pragma unroll
    for (int kc = 0; kc < 2; ++kc) {
      ushort8 a = *(const ushort8*)&Xs[w * 16 + l16][kc * 32 + lg * 8];
#pragma unroll
      for (int eg = 0; eg < 4; ++eg) {
        ushort8 bf = *(const ushort8*)&Ws[eg * 16 + l16][kc * 32 + lg * 8];
        acc[eg] = mfma16(a, bf, acc[eg]);
      }
    }

    if (m < 2) {
#pragma unroll
      for (int eg = 0; eg < 4; ++eg)
#pragma unroll
        for (int r = 0; r < 4; ++r)
          Os[w * 16 + lg * 4 + r][eg * 16 + l16] = f2bf(acc[eg][r]);
    } else {
#pragma unroll
      for (int eg = 0; eg < 4; ++eg) {
        uint2v pk;
        pk[0] = cvtpk(acc[eg][0], acc[eg][1]);
        pk[1] = cvtpk(acc[eg][2], acc[eg][3]);
        *(uint2v*)&Os[eg * 16 + l16][w * 16 + lg * 4] = pk;
      }
    }
    __syncthreads();  // Os ready; all Xs/Ws mfma reads retired

    if (m < 2) {
#pragma unroll
      for (int i = 0; i < 2; ++i) {
        int rw = i * 32 + (tid >> 3), c8 = (tid & 7) * 8;
        *(ushort8*)&op[((size_t)(b * H_ + h) * N_ + (nt0 + t) * 64 + rw) * 64 + c8] =
            *(const ushort8*)&Os[rw][c8];
      }
    } else {
#pragma unroll
      for (int i = 0; i < 2; ++i) {
        int rw = i * 32 + (tid >> 3), c8 = (tid & 7) * 8;
        *(ushort8*)&Vt[((size_t)bh * 64 + rw) * N_ + (nt0 + t) * 64 + c8] =
            *(const ushort8*)&Os[rw][c8];
      }
    }
  }
}

// ---------------- flash attention per (b,h,qtile=128) — R14 text verbatim ----------------
__global__ __launch_bounds__(256, 4) void attn_kernel(
    const unsigned short* __restrict__ Qh, const unsigned short* __restrict__ Kh,
    const unsigned short* __restrict__ Vt, const float* __restrict__ mask,
    unsigned short* __restrict__ attnO) {
  const int bid = blockIdx.x;
  const int logical = (bid & 7) * 192 + (bid >> 3);  // XCD-chunked swizzle (1536%8==0)
  const int qt = logical % 6;
  const int bh = logical / 6;
  const int b = bh >> 4, h = bh & 15;
  const int tid = threadIdx.x;
  const int w = tid >> 6, l = tid & 63;
  const int l16 = l & 15, lg = l >> 4;

  __shared__ __align__(16) unsigned short Ks[64][72];
  __shared__ __align__(16) unsigned short Vs[64][72];
  __shared__ float addk[N_];

  const size_t baseK = (size_t)bh * N_ * 64;  // Kh (B,H,N,D)
  const size_t baseV = (size_t)bh * 64 * N_;  // Vt (B,H,D,N)
  const int qrow0 = qt * 128 + w * 32;
  const float C2 = 0.04508422f;  // log2(e)/32

  for (int i = tid; i < N_; i += 256)
    addk[i] = (mask[h * N_ + i] < -1e30f) ? -1.0e20f : 0.0f;

  ushort8 bQ[2][2];
#pragma unroll
  for (int qs = 0; qs < 2; ++qs)
#pragma unroll
    for (int kc = 0; kc < 2; ++kc)
      bQ[qs][kc] = *(const ushort8*)&Qh[((size_t)bh * N_ + qrow0 + qs * 16 + l16) * 64 +
                                        kc * 32 + lg * 8];
  float bqf[2];
#pragma unroll
  for (int qs = 0; qs < 2; ++qs)
    bqf[qs] = (mask[h * N_ + qrow0 + qs * 16 + l16] < -1e30f) ? 1.f : 0.f;

  // all-ones B fragment (bf16 1.0 = 0x3F80): ones-MFMA gives row-sums of P
  ushort8 ones8;
#pragma unroll
  for (int i = 0; i < 8; ++i) ones8[i] = 0x3F80u;

  const int srow = tid >> 3;
  const int sc8 = (tid & 7) * 8;

  uint4v kreg[2], vreg[2];
#pragma unroll
  for (int i = 0; i < 2; ++i) {
    int row = i * 32 + srow;
    kreg[i] = *(const uint4v*)&Kh[baseK + (size_t)row * 64 + sc8];
    vreg[i] = *(const uint4v*)&Vt[baseV + (size_t)row * N_ + sc8];
  }
  __syncthreads();  // addk ready
#pragma unroll
  for (int i = 0; i < 2; ++i) {
    int row = i * 32 + srow;
    *(ushort8*)&Ks[row][sc8] = __builtin_bit_cast(ushort8, kreg[i]);
    *(ushort8*)&Vs[row][sc8] = __builtin_bit_cast(ushort8, vreg[i]);
  }
  __syncthreads();

  f32x4 oacc[2][4] = {};
  f32x4 dacc[2] = {};

  for (int kt = 0; kt < 12; ++kt) {
    if (kt < 11) {  // T14: issue next-tile loads early, write after barrier
#pragma unroll
      for (int i = 0; i < 2; ++i) {
        int row = i * 32 + srow;
        kreg[i] = *(const uint4v*)&Kh[baseK + (size_t)((kt + 1) * 64 + row) * 64 + sc8];
        vreg[i] = *(const uint4v*)&Vt[baseV + (size_t)row * N_ + (kt + 1) * 64 + sc8];
      }
    }

    f32x4 st[4][2] = {};
#pragma unroll
    for (int kc = 0; kc < 2; ++kc) {
#pragma unroll
      for (int cg = 0; cg < 4; ++cg) {
        ushort8 aK = *(const ushort8*)&Ks[cg * 16 + l16][kc * 32 + lg * 8];
        st[cg][0] = mfma16(aK, bQ[0][kc], st[cg][0]);
        st[cg][1] = mfma16(aK, bQ[1][kc], st[cg][1]);
      }
    }

#pragma unroll
    for (int cg = 0; cg < 4; ++cg) {
      f32x4 ak4 = *(const f32x4*)&addk[kt * 64 + cg * 16 + lg * 4];
#pragma unroll
      for (int qs = 0; qs < 2; ++qs) {
#pragma unroll
        for (int r = 0; r < 4; ++r) {
          float t = __builtin_fmaf(st[cg][qs][r], C2, ak4[r]);
          t = (bqf[qs] > 0.f) ? 0.0f : t;
          st[cg][qs][r] = fexp2(t);
        }
      }
    }

#pragma unroll
    for (int kcP = 0; kcP < 2; ++kcP) {
      ushort8 pa[2];
#pragma unroll
      for (int qs = 0; qs < 2; ++qs) {
        unsigned a0 = cvtpk(st[2 * kcP][qs][0], st[2 * kcP][qs][1]);
        unsigned b0 = cvtpk(st[2 * kcP][qs][2], st[2 * kcP][qs][3]);
        unsigned a1 = cvtpk(st[2 * kcP + 1][qs][0], st[2 * kcP + 1][qs][1]);
        unsigned b1 = cvtpk(st[2 * kcP + 1][qs][2], st[2 * kcP + 1][qs][3]);
        asm("v_permlane32_swap_b32 %0, %1" : "+v"(a0), "+v"(a1));
        asm("v_permlane16_swap_b32 %0, %1" : "+v"(a0), "+v"(a1));
        asm("v_permlane32_swap_b32 %0, %1" : "+v"(b0), "+v"(b1));
        asm("v_permlane16_swap_b32 %0, %1" : "+v"(b0), "+v"(b1));
        uint4v pk;
        pk[0] = a0; pk[1] = b0; pk[2] = a1; pk[3] = b1;
        pa[qs] = __builtin_bit_cast(ushort8, pk);
      }
#pragma unroll
      for (int dg = 0; dg < 4; ++dg) {
        ushort8 bv = *(const ushort8*)&Vs[dg * 16 + l16][kcP * 32 + lg * 8];
        oacc[0][dg] = mfma16(pa[0], bv, oacc[0][dg]);
        oacc[1][dg] = mfma16(pa[1], bv, oacc[1][dg]);
      }
      dacc[0] = mfma16(pa[0], ones8, dacc[0]);  // row-sum of P -> denom
      dacc[1] = mfma16(pa[1], ones8, dacc[1]);
    }

    __syncthreads();  // all waves done reading K/V tile
    if (kt < 11) {
#pragma unroll
      for (int i = 0; i < 2; ++i) {
        int row = i * 32 + srow;
        *(ushort8*)&Ks[row][sc8] = __builtin_bit_cast(ushort8, kreg[i]);
        *(ushort8*)&Vs[row][sc8] = __builtin_bit_cast(ushort8, vreg[i]);
      }
    }
    __syncthreads();  // next tile visible
  }

  // epilogue: dacc[qs][r] is already the denominator for q = qrow0+qs*16+lg*4+r
#pragma unroll
  for (int qs = 0; qs < 2; ++qs) {
#pragma unroll
    for (int r = 0; r < 4; ++r) {
      float inv = 1.f / dacc[qs][r];
      int qg = qrow0 + qs * 16 + lg * 4 + r;
      size_t orow = ((size_t)b * N_ + qg) * E_ + h * 64;
#pragma unroll
      for (int dg = 0; dg < 4; ++dg)
        attnO[orow + dg * 16 + l16] = f2bf(oacc[qs][dg][r] * inv);
    }
  }
}

// ---------------- final GEMM: out = attn @ Wf^T — R14 text verbatim ----------------
__global__ __launch_bounds__(256) void gemm_kernel(const unsigned short* __restrict__ A,
                                                   const unsigned short* __restrict__ Bm,
                                                   float* __restrict__ out) {
  const int be = blockIdx.x & 7;   // Wf panel per XCD (L2 locality)
  const int bm = blockIdx.x >> 3;
  const int tid = threadIdx.x;
  const int w = tid >> 6, l = tid & 63;
  const int l16 = l & 15, lg = l >> 4;
  const int wm = w >> 1, wn = w & 1;

  __shared__ __align__(16) unsigned short As[128][72];
  __shared__ __align__(16) unsigned short Bs[128][72];

  f32x4 acc[4][4] = {};
  const int m0 = bm * 128, e0 = be * 128;
  const int srow = tid >> 3, sc8 = (tid & 7) * 8;
  const unsigned short* Ab = A + (size_t)(m0 + srow) * E_ + sc8;
  const unsigned short* Bb = Bm + (size_t)(e0 + srow) * E_ + sc8;

  uint4v ar[4], br[4];
#pragma unroll
  for (int i = 0; i < 4; ++i) {
    ar[i] = *(const uint4v*)(Ab + (size_t)i * 32 * E_);
    br[i] = *(const uint4v*)(Bb + (size_t)i * 32 * E_);
  }

  for (int kk = 0; kk < 16; ++kk) {
    __syncthreads();  // prev-tile reads done
#pragma unroll
    for (int i = 0; i < 4; ++i) {
      *(ushort8*)&As[i * 32 + srow][sc8] = __builtin_bit_cast(ushort8, ar[i]);
      *(ushort8*)&Bs[i * 32 + srow][sc8] = __builtin_bit_cast(ushort8, br[i]);
    }
    __syncthreads();  // tile ready
    if (kk < 15) {    // issue next-tile loads; overlap with MFMAs below
#pragma unroll
      for (int i = 0; i < 4; ++i) {
        ar[i] = *(const uint4v*)(Ab + (size_t)i * 32 * E_ + (kk + 1) * 64);
        br[i] = *(const uint4v*)(Bb + (size_t)i * 32 * E_ + (kk + 1) * 64);
      }
    }
#pragma unroll
    for (int kc = 0; kc < 2; ++kc) {
      ushort8 a[4], bf[4];
#pragma unroll
      for (int i = 0; i < 4; ++i)
        a[i] = *(const ushort8*)&As[wm * 64 + i * 16 + l16][kc * 32 + lg * 8];
#pragma unroll
      for (int j = 0; j < 4; ++j)
        bf[j] = *(const ushort8*)&Bs[wn * 64 + j * 16 + l16][kc * 32 + lg * 8];
#pragma unroll
      for (int i = 0; i < 4; ++i)
#pragma unroll
        for (int j = 0; j < 4; ++j) acc[i][j] = mfma16(a[i], bf[j], acc[i][j]);
    }
  }

#pragma unroll
  for (int i = 0; i < 4; ++i)
#pragma unroll
    for (int j = 0; j < 4; ++j)
#pragma unroll
      for (int r = 0; r < 4; ++r)
        out[(size_t)(m0 + wm * 64 + i * 16 + lg * 4 + r) * E_ + e0 + wn * 64 + j * 16 + l16] =
            acc[i][j][r];
}

extern "C" void kernel_launch(void* const* d_in, const int* in_sizes, int n_in,
                              void* d_out, int out_size, void* d_ws, size_t ws_size,
                              hipStream_t stream) {
  const float* q = (const float*)d_in[0];
  const float* k = (const float*)d_in[1];
  const float* v = (const float*)d_in[2];
  const float* mask = (const float*)d_in[3];
  const float* Wq = (const float*)d_in[4];
  const float* Wk = (const float*)d_in[5];
  const float* Wv = (const float*)d_in[6];
  const float* Wf = (const float*)d_in[7];
  float* out = (float*)d_out;

  const size_t PH = (size_t)B_ * H_ * N_ * D_;
  unsigned short* Qh = (unsigned short*)d_ws;
  unsigned short* Kh = Qh + PH;
  unsigned short* Vt = Kh + PH;
  unsigned short* attn = Vt + PH;
  unsigned short* Wfb = attn + PH;

  proj_kernel<<<3 * B_ * H_ * (N_ / 256), 256, 0, stream>>>(q, k, v, Wq, Wk, Wv, Wf, Qh, Kh,
                                                            Vt, Wfb);
  attn_kernel<<<B_ * H_ * (N_ / 128), 256, 0, stream>>>(Qh, Kh, Vt, mask, attn);
  gemm_kernel<<<(B_ * N_ / 128) * (E_ / 128), 256, 0, stream>>>(attn, Wfb, out);
}